// Round 9
// baseline (291.102 us; speedup 1.0000x reference)
//
#include <hip/hip_runtime.h>
#include <hip/hip_bf16.h>
#include <hip/hip_fp16.h>

#define LEAK 0.2f

typedef _Float16 half8  __attribute__((ext_vector_type(8)));
typedef _Float16 half4v __attribute__((ext_vector_type(4)));
typedef float    float4v __attribute__((ext_vector_type(4)));

// ================= bucketed CSR build =================
// bucket b = dst >> 7 (128 nodes/bucket). NBK <= 512. packed: src | (dloc<<17)

__global__ __launch_bounds__(256) void k_bincount(const int* __restrict__ edst,
                                                  int* __restrict__ gbkt,
                                                  int E, int ETOT, int NBK) {
    __shared__ int lh[512];
    int t = threadIdx.x;
    for (int b = t; b < NBK; b += 256) lh[b] = 0;
    __syncthreads();
    int base = blockIdx.x * 4096;
    #pragma unroll
    for (int u = 0; u < 16; ++u) {
        int e = base + u * 256 + t;
        if (e < ETOT) {
            int d = (e < E) ? edst[e] : (e - E);
            atomicAdd(&lh[d >> 7], 1);
        }
    }
    __syncthreads();
    for (int b = t; b < NBK; b += 256)
        if (lh[b]) atomicAdd(&gbkt[b], lh[b]);
}

__global__ __launch_bounds__(512) void k_bktscan(const int* __restrict__ gbkt,
                                                 int* __restrict__ bko,
                                                 int* __restrict__ gcur, int NBK) {
    int t = threadIdx.x;
    int v = (t < NBK) ? gbkt[t] : 0;
    int lane = t & 63, wid = t >> 6;
    int x = v;
    #pragma unroll
    for (int o = 1; o < 64; o <<= 1) {
        int y = __shfl_up(x, o);
        if (lane >= o) x += y;
    }
    __shared__ int ws[8];
    if (lane == 63) ws[wid] = x;
    __syncthreads();
    if (wid == 0) {
        int s = (lane < 8) ? ws[lane] : 0;
        #pragma unroll
        for (int o = 1; o < 8; o <<= 1) {
            int y = __shfl_up(s, o);
            if (lane >= o) s += y;
        }
        if (lane < 8) ws[lane] = s;
    }
    __syncthreads();
    int excl = x - v + (wid > 0 ? ws[wid - 1] : 0);
    if (t < NBK) { bko[t] = excl; gcur[t] = excl; }
    if (t == 511) bko[NBK] = excl;
}

__global__ __launch_bounds__(256) void k_binscatter(const int* __restrict__ esrc,
                                                    const int* __restrict__ edst,
                                                    int* __restrict__ gcur,
                                                    unsigned int* __restrict__ binned,
                                                    int E, int ETOT, int NBK) {
    __shared__ int lh[512];
    __shared__ int lbase[512];
    int t = threadIdx.x;
    for (int b = t; b < NBK; b += 256) lh[b] = 0;
    __syncthreads();
    int base = blockIdx.x * 4096;
    unsigned int word[16]; int bb[16], rk[16];
    #pragma unroll
    for (int u = 0; u < 16; ++u) {
        int e = base + u * 256 + t;
        bb[u] = -1;
        if (e < ETOT) {
            int s, d;
            if (e < E) { s = esrc[e]; d = edst[e]; } else { s = d = e - E; }
            int b = d >> 7;
            bb[u] = b;
            rk[u] = atomicAdd(&lh[b], 1);
            word[u] = (unsigned int)s | ((unsigned int)(d & 127) << 17);
        }
    }
    __syncthreads();
    for (int b = t; b < NBK; b += 256) {
        int c = lh[b];
        lbase[b] = c ? atomicAdd(&gcur[b], c) : 0;
    }
    __syncthreads();
    #pragma unroll
    for (int u = 0; u < 16; ++u)
        if (bb[u] >= 0) binned[lbase[bb[u]] + rk[u]] = word[u];
}

// fused: per-bucket degree count + LDS scan -> off[] + scatter into csr
__global__ __launch_bounds__(256) void k_scatter2(const unsigned int* __restrict__ binned,
                                                  const int* __restrict__ bko,
                                                  int* __restrict__ off,
                                                  int* __restrict__ csr, int N, int NBK) {
    __shared__ int deg[128];
    __shared__ int lcur[128];
    __shared__ int wt[2];
    int b = blockIdx.x, t = threadIdx.x;
    int n0 = b << 7;
    if (t < 128) deg[t] = 0;
    __syncthreads();
    int beg = bko[b], end = bko[b + 1];
    for (int i = beg + t; i < end; i += 256)
        atomicAdd(&deg[binned[i] >> 17], 1);
    __syncthreads();
    int v = 0, x = 0;
    if (t < 128) {
        v = deg[t];
        x = v;
        int lane = t & 63;
        #pragma unroll
        for (int o = 1; o < 64; o <<= 1) {
            int y = __shfl_up(x, o);
            if (lane >= o) x += y;
        }
        if (lane == 63) wt[t >> 6] = x;
    }
    __syncthreads();
    if (t < 128) {
        int excl = x - v + ((t >= 64) ? wt[0] : 0) + beg;
        lcur[t] = excl;
        int node = n0 + t;
        if (node < N) off[node] = excl;
    }
    if (b == NBK - 1 && t == 0) off[N] = end;
    __syncthreads();
    for (int i = beg + t; i < end; i += 256) {
        unsigned int u = binned[i];
        int pos = atomicAdd(&lcur[u >> 17], 1);
        csr[pos] = (int)(u & 0x1FFFF);
    }
}

// ================= W -> fp16 TRANSPOSED (w16t[n*128+k]) =================

__global__ __launch_bounds__(256) void k_wconv(const float* __restrict__ W0,
                                               const float* __restrict__ W1,
                                               const float* __restrict__ W2,
                                               _Float16* __restrict__ w16t) {
    __shared__ _Float16 tile[64][68];
    int m = blockIdx.x >> 2;
    int ti = (blockIdx.x >> 1) & 1, tj = blockIdx.x & 1;
    const float* src = (m == 0) ? W0 : (m == 1 ? W1 : W2);
    _Float16* dst = w16t + m * 16384;
    int t = threadIdx.x;
    for (int idx = t; idx < 4096; idx += 256) {
        int r = idx >> 6, c = idx & 63;
        tile[r][c] = (_Float16)src[(ti * 64 + r) * 128 + tj * 64 + c];
    }
    __syncthreads();
    for (int idx = t; idx < 4096; idx += 256) {
        int c = idx >> 6, r = idx & 63;
        dst[(tj * 64 + c) * 128 + ti * 64 + r] = tile[r][c];
    }
}

// ================= MFMA fp16 GEMM + fused attention logits =================
// X input either fp32 (layer 1) or fp16 (layers 2/3, from aggregate).
// 16x16x32_f16 lane maps (m89-verified):
//   A[m][k]: m=lane&15, k=(lane>>4)*8+j ; B[k][n]: n=lane&15, k=(lane>>4)*8+j
//   C/D[r][c]: c=lane&15, r=(lane>>4)*4+reg

__global__ __launch_bounds__(256) void k_gemm_mfma(const void* __restrict__ Xv, int xfp16,
                                                   const _Float16* __restrict__ WhT,
                                                   const float* __restrict__ a_src,
                                                   const float* __restrict__ a_dst,
                                                   _Float16* __restrict__ Hout,
                                                   float* __restrict__ alsrc,
                                                   float* __restrict__ aldst, int N) {
    __shared__ _Float16 As[64][136];   // row stride 272 B (16-aligned); pad -> 2-way alias only
    __shared__ float sS[64][2];
    __shared__ float sD[64][2];
    const int t = threadIdx.x;
    const int lane = t & 63, w = t >> 6;
    const int block_row = blockIdx.x * 64;

    if (t < 128) { sS[t >> 1][t & 1] = 0.f; sD[t >> 1][t & 1] = 0.f; }

    if (xfp16) {
        const _Float16* Xh = (const _Float16*)Xv;
        #pragma unroll
        for (int it = 0; it < 4; ++it) {
            int i = t + 256 * it;
            int row = i >> 4, c8 = i & 15;
            int gr = block_row + row;
            half8 hv = (half8){0,0,0,0,0,0,0,0};
            if (gr < N) hv = *(const half8*)(Xh + (size_t)gr * 128 + c8 * 8);
            *(half8*)(&As[row][c8 * 8]) = hv;
        }
    } else {
        const float* X = (const float*)Xv;
        #pragma unroll
        for (int it = 0; it < 8; ++it) {
            int i = t + 256 * it;
            int row = i >> 5, c4 = i & 31;
            int gr = block_row + row;
            float4 xv = make_float4(0.f, 0.f, 0.f, 0.f);
            if (gr < N) xv = *(const float4*)(X + (size_t)gr * 128 + c4 * 4);
            half4v hv;
            hv[0] = (_Float16)xv.x; hv[1] = (_Float16)xv.y;
            hv[2] = (_Float16)xv.z; hv[3] = (_Float16)xv.w;
            *(half4v*)(&As[row][c4 * 4]) = hv;
        }
    }

    const int l15 = lane & 15, kq = (lane >> 4) * 8;
    half8 bf[2][4];
    #pragma unroll
    for (int ntl = 0; ntl < 2; ++ntl) {
        int n0 = (w * 2 + ntl) * 16 + l15;
        #pragma unroll
        for (int kt = 0; kt < 4; ++kt)
            bf[ntl][kt] = *(const half8*)(WhT + (size_t)n0 * 128 + kt * 32 + kq);
    }
    __syncthreads();

    float4v acc[4][2];
    #pragma unroll
    for (int mt = 0; mt < 4; ++mt)
        #pragma unroll
        for (int ntl = 0; ntl < 2; ++ntl)
            acc[mt][ntl] = (float4v){0.f, 0.f, 0.f, 0.f};

    #pragma unroll
    for (int kt = 0; kt < 4; ++kt) {
        half8 a[4];
        #pragma unroll
        for (int mt = 0; mt < 4; ++mt)
            a[mt] = *(const half8*)(&As[mt * 16 + l15][kt * 32 + kq]);
        #pragma unroll
        for (int mt = 0; mt < 4; ++mt)
            #pragma unroll
            for (int ntl = 0; ntl < 2; ++ntl)
                acc[mt][ntl] = __builtin_amdgcn_mfma_f32_16x16x32_f16(
                    a[mt], bf[ntl][kt], acc[mt][ntl], 0, 0, 0);
    }

    #pragma unroll
    for (int mt = 0; mt < 4; ++mt) {
        int r0 = block_row + mt * 16 + (lane >> 4) * 4;
        #pragma unroll
        for (int ntl = 0; ntl < 2; ++ntl) {
            int col = (w * 2 + ntl) * 16 + l15;
            #pragma unroll
            for (int reg = 0; reg < 4; ++reg) {
                int r = r0 + reg;
                if (r < N) Hout[(size_t)r * 128 + col] = (_Float16)acc[mt][ntl][reg];
            }
        }
    }

    // fused attention logits: wave covers cols [w*32, w*32+32) -> head = w>>1
    {
        int c0 = w * 32 + l15, c1 = c0 + 16;
        float as0 = a_src[c0], as1 = a_src[c1];
        float ad0 = a_dst[c0], ad1 = a_dst[c1];
        int head = w >> 1;
        #pragma unroll
        for (int mt = 0; mt < 4; ++mt) {
            #pragma unroll
            for (int reg = 0; reg < 4; ++reg) {
                float ps = (float)acc[mt][0][reg] * as0 + (float)acc[mt][1][reg] * as1;
                float pd = (float)acc[mt][0][reg] * ad0 + (float)acc[mt][1][reg] * ad1;
                #pragma unroll
                for (int o = 1; o < 16; o <<= 1) {
                    ps += __shfl_xor(ps, o);
                    pd += __shfl_xor(pd, o);
                }
                if (l15 == 0) {
                    int row = mt * 16 + (lane >> 4) * 4 + reg;
                    atomicAdd(&sS[row][head], ps);
                    atomicAdd(&sD[row][head], pd);
                }
            }
        }
    }
    __syncthreads();
    if (t < 128) {
        int row = t >> 1, head = t & 1;
        int gr = block_row + row;
        if (gr < N) {
            alsrc[gr * 2 + head] = sS[row][head];
            aldst[gr * 2 + head] = sD[row][head];
        }
    }
}

// ================= softmax-aggregate: TWO nodes per wave64, 4-deep MLP ============
// half = lane>>5 picks node; hl = lane&31; p = hl&15 owns ch [8p,8p+8); q = hl>>4
// picks edges == q (mod 2). fp16 Out/prev. No segment-max (logits bounded).
// mode: 0 = bias->Out ; 1 = bias+prev->Out ; 2 = bias+prev, fused lin dot -> logits

__global__ __launch_bounds__(256) void k_aggregate(
        const _Float16* __restrict__ H16,   // [N][128] fp16
        const float* __restrict__ alsrc,
        const float* __restrict__ aldst,
        const int* __restrict__ off, const int* __restrict__ csr,
        const float* __restrict__ bias,
        const _Float16* __restrict__ prev,  // fp16 residual input
        _Float16* __restrict__ Out,         // fp16 activation output
        const float* __restrict__ lw, const float* __restrict__ lb,
        float* __restrict__ logits, int N, int mode) {
    int wglobal = (int)((blockIdx.x * 256 + threadIdx.x) >> 6);
    int lane = threadIdx.x & 63;
    if (wglobal * 2 >= N) return;
    int half = lane >> 5;
    int hl = lane & 31;
    int node = wglobal * 2 + half;
    bool active = node < N;
    int nodeC = active ? node : (N - 1);
    int beg = off[nodeC];
    int end = active ? off[nodeC + 1] : beg;
    float ad0 = aldst[nodeC * 2], ad1 = aldst[nodeC * 2 + 1];

    int p = hl & 15;
    int q = hl >> 4;
    bool head0 = p < 8;
    const _Float16* hbase = H16 + p * 8;
    int hb = half << 5;

    float acc[8];
    #pragma unroll
    for (int k = 0; k < 8; ++k) acc[k] = 0.f;
    float dsum = 0.f;

    for (int base = beg; base < end; base += 32) {
        int i = base + hl;
        int s = 0; float w0 = 0.f, w1 = 0.f;
        if (i < end) {
            s = csr[i];
            float2 al = *(const float2*)(&alsrc[s * 2]);
            float e0 = al.x + ad0; e0 = e0 > 0.f ? e0 : LEAK * e0;
            float e1 = al.y + ad1; e1 = e1 > 0.f ? e1 : LEAK * e1;
            w0 = __expf(e0); w1 = __expf(e1);
        }
        int cnt = min(32, end - base);
        int iters = (cnt + 1) >> 1;
        int jj = 0;
        // 4 independent 16-B gathers in flight per half-wave (8 per wave)
        for (; jj + 4 <= iters; jj += 4) {
            int sl0 = hb + (jj << 1) + q;
            int sj0 = __shfl(s, sl0), sj1 = __shfl(s, sl0 + 2);
            int sj2 = __shfl(s, sl0 + 4), sj3 = __shfl(s, sl0 + 6);
            float w00 = __shfl(w0, sl0),     w10 = __shfl(w1, sl0);
            float w01 = __shfl(w0, sl0 + 2), w11 = __shfl(w1, sl0 + 2);
            float w02 = __shfl(w0, sl0 + 4), w12 = __shfl(w1, sl0 + 4);
            float w03 = __shfl(w0, sl0 + 6), w13 = __shfl(w1, sl0 + 6);
            float ws0 = head0 ? w00 : w10;
            float ws1 = head0 ? w01 : w11;
            float ws2 = head0 ? w02 : w12;
            float ws3 = head0 ? w03 : w13;
            uint4 r0 = *(const uint4*)(hbase + (size_t)sj0 * 128);
            uint4 r1 = *(const uint4*)(hbase + (size_t)sj1 * 128);
            uint4 r2 = *(const uint4*)(hbase + (size_t)sj2 * 128);
            uint4 r3 = *(const uint4*)(hbase + (size_t)sj3 * 128);
            const _Float16* h0 = (const _Float16*)&r0;
            const _Float16* h1 = (const _Float16*)&r1;
            const _Float16* h2 = (const _Float16*)&r2;
            const _Float16* h3 = (const _Float16*)&r3;
            #pragma unroll
            for (int k = 0; k < 8; ++k) acc[k] += ws0 * (float)h0[k];
            #pragma unroll
            for (int k = 0; k < 8; ++k) acc[k] += ws1 * (float)h1[k];
            #pragma unroll
            for (int k = 0; k < 8; ++k) acc[k] += ws2 * (float)h2[k];
            #pragma unroll
            for (int k = 0; k < 8; ++k) acc[k] += ws3 * (float)h3[k];
            dsum += (ws0 + ws1) + (ws2 + ws3);
        }
        for (; jj + 2 <= iters; jj += 2) {
            int sl0 = hb + (jj << 1) + q;
            int sj0 = __shfl(s, sl0), sj1 = __shfl(s, sl0 + 2);
            float w00 = __shfl(w0, sl0),     w10 = __shfl(w1, sl0);
            float w01 = __shfl(w0, sl0 + 2), w11 = __shfl(w1, sl0 + 2);
            float ws0 = head0 ? w00 : w10;
            float ws1 = head0 ? w01 : w11;
            uint4 r0 = *(const uint4*)(hbase + (size_t)sj0 * 128);
            uint4 r1 = *(const uint4*)(hbase + (size_t)sj1 * 128);
            const _Float16* h0 = (const _Float16*)&r0;
            const _Float16* h1 = (const _Float16*)&r1;
            #pragma unroll
            for (int k = 0; k < 8; ++k) acc[k] += ws0 * (float)h0[k];
            #pragma unroll
            for (int k = 0; k < 8; ++k) acc[k] += ws1 * (float)h1[k];
            dsum += ws0 + ws1;
        }
        if (jj < iters) {
            int sl = hb + (jj << 1) + q;
            int   sj = __shfl(s,  sl);
            float wa = __shfl(w0, sl);
            float wb = __shfl(w1, sl);
            float ws = head0 ? wa : wb;
            uint4 raw = *(const uint4*)(hbase + (size_t)sj * 128);
            const _Float16* h = (const _Float16*)&raw;
            #pragma unroll
            for (int k = 0; k < 8; ++k) acc[k] += ws * (float)h[k];
            dsum += ws;
        }
    }

    // merge the two q-groups within each half (NOT across halves!)
    #pragma unroll
    for (int k = 0; k < 8; ++k) acc[k] += __shfl_xor(acc[k], 16);
    dsum += __shfl_xor(dsum, 16);

    if (q == 0 && active) {
        float inv = 1.f / dsum;
        int c0 = p * 8;
        float v[8];
        #pragma unroll
        for (int k = 0; k < 8; ++k) v[k] = acc[k] * inv + bias[c0 + k];
        if (mode >= 1) {
            half8 pv = *(const half8*)(prev + (size_t)node * 128 + c0);
            #pragma unroll
            for (int k = 0; k < 8; ++k) v[k] += (float)pv[k];
        }
        #pragma unroll
        for (int k = 0; k < 8; ++k) v[k] = v[k] > 0.f ? v[k] : LEAK * v[k];
        if (mode == 2) {
            float partial = 0.f;
            #pragma unroll
            for (int k = 0; k < 8; ++k) partial += v[k] * lw[c0 + k];
            partial += __shfl_xor(partial, 1);
            partial += __shfl_xor(partial, 2);
            partial += __shfl_xor(partial, 4);
            partial += __shfl_xor(partial, 8);
            if (hl == 0) logits[node] = partial + lb[0];
        } else {
            half8 ov;
            #pragma unroll
            for (int k = 0; k < 8; ++k) ov[k] = (_Float16)v[k];
            *(half8*)(Out + (size_t)node * 128 + c0) = ov;
        }
    }
}

// ================= launch =================

extern "C" void kernel_launch(void* const* d_in, const int* in_sizes, int n_in,
                              void* d_out, int out_size, void* d_ws, size_t ws_size,
                              hipStream_t stream) {
    const float* x    = (const float*)d_in[0];
    const int*   edge = (const int*)d_in[1];
    const float* W[3]  = {(const float*)d_in[2], (const float*)d_in[6], (const float*)d_in[10]};
    const float* as[3] = {(const float*)d_in[3], (const float*)d_in[7], (const float*)d_in[11]};
    const float* ad[3] = {(const float*)d_in[4], (const float*)d_in[8], (const float*)d_in[12]};
    const float* bs[3] = {(const float*)d_in[5], (const float*)d_in[9], (const float*)d_in[13]};
    const float* lw = (const float*)d_in[14];
    const float* lb = (const float*)d_in[15];

    const int N    = in_sizes[0] / 128;
    const int E    = in_sizes[1] / 2;
    const int ETOT = E + N;
    const int NBK  = (N + 127) >> 7;   // requires N <= 65536 (here N = 50000)

    char* base = (char*)d_ws;
    size_t o = 0;
    auto carve = [&](size_t bytes) {
        char* p = base + o;
        o = (o + bytes + 255) & ~(size_t)255;
        return p;
    };
    int*      off    = (int*)     carve((size_t)(N + 1) * 4);
    int*      gbkt   = (int*)     carve((size_t)(NBK + 1) * 4);
    int*      bko    = (int*)     carve((size_t)(NBK + 1) * 4);
    int*      gcur   = (int*)     carve((size_t)(NBK + 1) * 4);
    unsigned* binned = (unsigned*)carve((size_t)ETOT * 4);
    int*      csr    = (int*)     carve((size_t)ETOT * 4);
    float*    alsrc  = (float*)   carve((size_t)N * 2 * 4);
    float*    aldst  = (float*)   carve((size_t)N * 2 * 4);
    _Float16* h16    = (_Float16*)carve((size_t)N * 128 * 2);
    _Float16* bufA   = (_Float16*)carve((size_t)N * 128 * 2);
    _Float16* bufB   = (_Float16*)carve((size_t)N * 128 * 2);
    _Float16* w16t   = (_Float16*)carve((size_t)3 * 16384 * 2);
    (void)ws_size; (void)n_in; (void)out_size;

    const int* esrc = edge;
    const int* edst = edge + E;

    int eb = (ETOT + 4095) / 4096;

    hipMemsetAsync(gbkt, 0, (size_t)(NBK + 1) * 4, stream);
    k_wconv<<<12, 256, 0, stream>>>(W[0], W[1], W[2], w16t);

    // bucketed CSR build (4 dispatches)
    k_bincount<<<eb, 256, 0, stream>>>(edst, gbkt, E, ETOT, NBK);
    k_bktscan<<<1, 512, 0, stream>>>(gbkt, bko, gcur, NBK);
    k_binscatter<<<eb, 256, 0, stream>>>(esrc, edst, gcur, binned, E, ETOT, NBK);
    k_scatter2<<<NBK, 256, 0, stream>>>(binned, bko, off, csr, N, NBK);

    int gemm_blocks = (N + 63) / 64;
    int agg_blocks  = (N + 7) / 8;     // 2 nodes per wave, 4 waves per block

    // layer 1 (fp32 input)
    k_gemm_mfma<<<gemm_blocks, 256, 0, stream>>>(x, 0, w16t, as[0], ad[0], h16, alsrc, aldst, N);
    k_aggregate<<<agg_blocks, 256, 0, stream>>>(h16, alsrc, aldst, off, csr,
                                                bs[0], nullptr, bufA, lw, lb, nullptr, N, 0);
    // layer 2 (fp16 input)
    k_gemm_mfma<<<gemm_blocks, 256, 0, stream>>>(bufA, 1, w16t + 16384, as[1], ad[1], h16, alsrc, aldst, N);
    k_aggregate<<<agg_blocks, 256, 0, stream>>>(h16, alsrc, aldst, off, csr,
                                                bs[1], bufA, bufB, lw, lb, nullptr, N, 1);
    // layer 3 (fp16 input, + fused final linear)
    k_gemm_mfma<<<gemm_blocks, 256, 0, stream>>>(bufB, 1, w16t + 32768, as[2], ad[2], h16, alsrc, aldst, N);
    k_aggregate<<<agg_blocks, 256, 0, stream>>>(h16, alsrc, aldst, off, csr,
                                                bs[2], bufB, nullptr, lw, lb, (float*)d_out, N, 2);
}

// Round 10
// 276.513 us; speedup vs baseline: 1.0528x; 1.0528x over previous
//
#include <hip/hip_runtime.h>
#include <hip/hip_bf16.h>
#include <hip/hip_fp16.h>

#define LEAK 0.2f
#define BCAP 4096   // edges per 128-node bucket; mean ~2176 for E/N=17, +40 sigma safe

typedef _Float16 half8  __attribute__((ext_vector_type(8)));
typedef _Float16 half4v __attribute__((ext_vector_type(4)));
typedef float    float4v __attribute__((ext_vector_type(4)));

// ================= bucketed CSR build (fixed-capacity buckets) =================
// bucket b = dst >> 7 (128 nodes/bucket). packed word: src | (dloc<<17).
// binned/csr are bucket-strided: bucket b occupies [b*BCAP, b*BCAP + cnt_b).

// fused: edge binning (blocks < eb) + W->fp16 transpose (blocks >= eb)
__global__ __launch_bounds__(256) void k_binscatter(const int* __restrict__ esrc,
                                                    const int* __restrict__ edst,
                                                    int* __restrict__ gcnt,
                                                    unsigned int* __restrict__ binned,
                                                    int E, int ETOT, int NBK, int eb,
                                                    const float* __restrict__ W0,
                                                    const float* __restrict__ W1,
                                                    const float* __restrict__ W2,
                                                    _Float16* __restrict__ w16t) {
    int t = threadIdx.x;
    if (blockIdx.x >= eb) {
        // ---- W transpose part: 12 blocks, 3 matrices x 4 (64x64) tiles ----
        __shared__ _Float16 tile[64][68];
        int bb = blockIdx.x - eb;
        int m = bb >> 2;
        int ti = (bb >> 1) & 1, tj = bb & 1;
        const float* src = (m == 0) ? W0 : (m == 1 ? W1 : W2);
        _Float16* dst = w16t + m * 16384;
        for (int idx = t; idx < 4096; idx += 256) {
            int r = idx >> 6, c = idx & 63;
            tile[r][c] = (_Float16)src[(ti * 64 + r) * 128 + tj * 64 + c];
        }
        __syncthreads();
        for (int idx = t; idx < 4096; idx += 256) {
            int c = idx >> 6, r = idx & 63;
            dst[(tj * 64 + c) * 128 + ti * 64 + r] = tile[r][c];
        }
        return;
    }
    __shared__ int lh[512];
    __shared__ int lbase[512];
    for (int b = t; b < NBK; b += 256) lh[b] = 0;
    __syncthreads();
    int base = blockIdx.x * 4096;
    unsigned int word[16]; int bb[16], rk[16];
    #pragma unroll
    for (int u = 0; u < 16; ++u) {
        int e = base + u * 256 + t;
        bb[u] = -1;
        if (e < ETOT) {
            int s, d;
            if (e < E) { s = esrc[e]; d = edst[e]; } else { s = d = e - E; }
            int b = d >> 7;
            bb[u] = b;
            rk[u] = atomicAdd(&lh[b], 1);
            word[u] = (unsigned int)s | ((unsigned int)(d & 127) << 17);
        }
    }
    __syncthreads();
    for (int b = t; b < NBK; b += 256) {
        int c = lh[b];
        lbase[b] = c ? atomicAdd(&gcnt[b], c) : 0;
    }
    __syncthreads();
    #pragma unroll
    for (int u = 0; u < 16; ++u)
        if (bb[u] >= 0)
            binned[(size_t)bb[u] * BCAP + lbase[bb[u]] + rk[u]] = word[u];
}

// per-bucket: degree count + LDS scan -> off[]/endv[] + scatter into bucket-strided csr
__global__ __launch_bounds__(256) void k_scatter2(const unsigned int* __restrict__ binned,
                                                  const int* __restrict__ gcnt,
                                                  int* __restrict__ off,
                                                  int* __restrict__ endv,
                                                  int* __restrict__ csr, int N) {
    __shared__ int deg[128];
    __shared__ int lcur[128];
    __shared__ int wt[2];
    int b = blockIdx.x, t = threadIdx.x;
    int n0 = b << 7;
    if (t < 128) deg[t] = 0;
    __syncthreads();
    int beg = b * BCAP, end = beg + gcnt[b];
    for (int i = beg + t; i < end; i += 256)
        atomicAdd(&deg[binned[i] >> 17], 1);
    __syncthreads();
    int v = 0, x = 0;
    if (t < 128) {
        v = deg[t];
        x = v;
        int lane = t & 63;
        #pragma unroll
        for (int o = 1; o < 64; o <<= 1) {
            int y = __shfl_up(x, o);
            if (lane >= o) x += y;
        }
        if (lane == 63) wt[t >> 6] = x;
    }
    __syncthreads();
    if (t < 128) {
        int excl = x - v + ((t >= 64) ? wt[0] : 0) + beg;
        lcur[t] = excl;
        int node = n0 + t;
        if (node < N) { off[node] = excl; endv[node] = excl + v; }
    }
    __syncthreads();
    for (int i = beg + t; i < end; i += 256) {
        unsigned int u = binned[i];
        int pos = atomicAdd(&lcur[u >> 17], 1);
        csr[pos] = (int)(u & 0x1FFFF);
    }
}

// ================= MFMA fp16 GEMM + fused attention logits =================
// X input either fp32 (layer 1) or fp16 (layers 2/3, from aggregate).
// 16x16x32_f16 lane maps (m89-verified):
//   A[m][k]: m=lane&15, k=(lane>>4)*8+j ; B[k][n]: n=lane&15, k=(lane>>4)*8+j
//   C/D[r][c]: c=lane&15, r=(lane>>4)*4+reg

__global__ __launch_bounds__(256) void k_gemm_mfma(const void* __restrict__ Xv, int xfp16,
                                                   const _Float16* __restrict__ WhT,
                                                   const float* __restrict__ a_src,
                                                   const float* __restrict__ a_dst,
                                                   _Float16* __restrict__ Hout,
                                                   float* __restrict__ alsrc,
                                                   float* __restrict__ aldst, int N) {
    __shared__ _Float16 As[64][136];   // +8 pad -> 2-way bank aliasing only (free)
    __shared__ float sS[64][2];
    __shared__ float sD[64][2];
    const int t = threadIdx.x;
    const int lane = t & 63, w = t >> 6;
    const int block_row = blockIdx.x * 64;

    if (t < 128) { sS[t >> 1][t & 1] = 0.f; sD[t >> 1][t & 1] = 0.f; }

    if (xfp16) {
        const _Float16* Xh = (const _Float16*)Xv;
        #pragma unroll
        for (int it = 0; it < 4; ++it) {
            int i = t + 256 * it;
            int row = i >> 4, c8 = i & 15;
            int gr = block_row + row;
            half8 hv = (half8){0,0,0,0,0,0,0,0};
            if (gr < N) hv = *(const half8*)(Xh + (size_t)gr * 128 + c8 * 8);
            *(half8*)(&As[row][c8 * 8]) = hv;
        }
    } else {
        const float* X = (const float*)Xv;
        #pragma unroll
        for (int it = 0; it < 8; ++it) {
            int i = t + 256 * it;
            int row = i >> 5, c4 = i & 31;
            int gr = block_row + row;
            float4 xv = make_float4(0.f, 0.f, 0.f, 0.f);
            if (gr < N) xv = *(const float4*)(X + (size_t)gr * 128 + c4 * 4);
            half4v hv;
            hv[0] = (_Float16)xv.x; hv[1] = (_Float16)xv.y;
            hv[2] = (_Float16)xv.z; hv[3] = (_Float16)xv.w;
            *(half4v*)(&As[row][c4 * 4]) = hv;
        }
    }

    const int l15 = lane & 15, kq = (lane >> 4) * 8;
    half8 bf[2][4];
    #pragma unroll
    for (int ntl = 0; ntl < 2; ++ntl) {
        int n0 = (w * 2 + ntl) * 16 + l15;
        #pragma unroll
        for (int kt = 0; kt < 4; ++kt)
            bf[ntl][kt] = *(const half8*)(WhT + (size_t)n0 * 128 + kt * 32 + kq);
    }
    __syncthreads();

    float4v acc[4][2];
    #pragma unroll
    for (int mt = 0; mt < 4; ++mt)
        #pragma unroll
        for (int ntl = 0; ntl < 2; ++ntl)
            acc[mt][ntl] = (float4v){0.f, 0.f, 0.f, 0.f};

    #pragma unroll
    for (int kt = 0; kt < 4; ++kt) {
        half8 a[4];
        #pragma unroll
        for (int mt = 0; mt < 4; ++mt)
            a[mt] = *(const half8*)(&As[mt * 16 + l15][kt * 32 + kq]);
        #pragma unroll
        for (int mt = 0; mt < 4; ++mt)
            #pragma unroll
            for (int ntl = 0; ntl < 2; ++ntl)
                acc[mt][ntl] = __builtin_amdgcn_mfma_f32_16x16x32_f16(
                    a[mt], bf[ntl][kt], acc[mt][ntl], 0, 0, 0);
    }

    #pragma unroll
    for (int mt = 0; mt < 4; ++mt) {
        int r0 = block_row + mt * 16 + (lane >> 4) * 4;
        #pragma unroll
        for (int ntl = 0; ntl < 2; ++ntl) {
            int col = (w * 2 + ntl) * 16 + l15;
            #pragma unroll
            for (int reg = 0; reg < 4; ++reg) {
                int r = r0 + reg;
                if (r < N) Hout[(size_t)r * 128 + col] = (_Float16)acc[mt][ntl][reg];
            }
        }
    }

    // fused attention logits: wave covers cols [w*32, w*32+32) -> head = w>>1
    {
        int c0 = w * 32 + l15, c1 = c0 + 16;
        float as0 = a_src[c0], as1 = a_src[c1];
        float ad0 = a_dst[c0], ad1 = a_dst[c1];
        int head = w >> 1;
        #pragma unroll
        for (int mt = 0; mt < 4; ++mt) {
            #pragma unroll
            for (int reg = 0; reg < 4; ++reg) {
                float ps = (float)acc[mt][0][reg] * as0 + (float)acc[mt][1][reg] * as1;
                float pd = (float)acc[mt][0][reg] * ad0 + (float)acc[mt][1][reg] * ad1;
                #pragma unroll
                for (int o = 1; o < 16; o <<= 1) {
                    ps += __shfl_xor(ps, o);
                    pd += __shfl_xor(pd, o);
                }
                if (l15 == 0) {
                    int row = mt * 16 + (lane >> 4) * 4 + reg;
                    atomicAdd(&sS[row][head], ps);
                    atomicAdd(&sD[row][head], pd);
                }
            }
        }
    }
    __syncthreads();
    if (t < 128) {
        int row = t >> 1, head = t & 1;
        int gr = block_row + row;
        if (gr < N) {
            alsrc[gr * 2 + head] = sS[row][head];
            aldst[gr * 2 + head] = sD[row][head];
        }
    }
}

// ================= softmax-aggregate: TWO nodes per wave64 =================
// half = lane>>5 picks node; hl = lane&31; p = hl&15 owns ch [8p,8p+8); q = hl>>4
// picks edges == q (mod 2). fp16 Out/prev. No segment-max (logits bounded).
// mode: 0 = bias->Out ; 1 = bias+prev->Out ; 2 = bias+prev, fused lin dot -> logits

__global__ __launch_bounds__(256) void k_aggregate(
        const _Float16* __restrict__ H16,   // [N][128] fp16
        const float* __restrict__ alsrc,
        const float* __restrict__ aldst,
        const int* __restrict__ off, const int* __restrict__ endv,
        const int* __restrict__ csr,
        const float* __restrict__ bias,
        const _Float16* __restrict__ prev,  // fp16 residual input
        _Float16* __restrict__ Out,         // fp16 activation output
        const float* __restrict__ lw, const float* __restrict__ lb,
        float* __restrict__ logits, int N, int mode) {
    int wglobal = (int)((blockIdx.x * 256 + threadIdx.x) >> 6);
    int lane = threadIdx.x & 63;
    if (wglobal * 2 >= N) return;
    int half = lane >> 5;
    int hl = lane & 31;
    int node = wglobal * 2 + half;
    bool active = node < N;
    int nodeC = active ? node : (N - 1);
    int beg = off[nodeC];
    int end = active ? endv[nodeC] : beg;
    float ad0 = aldst[nodeC * 2], ad1 = aldst[nodeC * 2 + 1];

    int p = hl & 15;
    int q = hl >> 4;
    bool head0 = p < 8;
    const _Float16* hbase = H16 + p * 8;
    int hb = half << 5;

    float acc[8];
    #pragma unroll
    for (int k = 0; k < 8; ++k) acc[k] = 0.f;
    float dsum = 0.f;

    for (int base = beg; base < end; base += 32) {
        int i = base + hl;
        int s = 0; float w0 = 0.f, w1 = 0.f;
        if (i < end) {
            s = csr[i];
            float2 al = *(const float2*)(&alsrc[s * 2]);
            float e0 = al.x + ad0; e0 = e0 > 0.f ? e0 : LEAK * e0;
            float e1 = al.y + ad1; e1 = e1 > 0.f ? e1 : LEAK * e1;
            w0 = __expf(e0); w1 = __expf(e1);
        }
        int cnt = min(32, end - base);
        int iters = (cnt + 1) >> 1;
        int jj = 0;
        for (; jj + 4 <= iters; jj += 4) {
            int sl0 = hb + (jj << 1) + q;
            int sj0 = __shfl(s, sl0), sj1 = __shfl(s, sl0 + 2);
            int sj2 = __shfl(s, sl0 + 4), sj3 = __shfl(s, sl0 + 6);
            float w00 = __shfl(w0, sl0),     w10 = __shfl(w1, sl0);
            float w01 = __shfl(w0, sl0 + 2), w11 = __shfl(w1, sl0 + 2);
            float w02 = __shfl(w0, sl0 + 4), w12 = __shfl(w1, sl0 + 4);
            float w03 = __shfl(w0, sl0 + 6), w13 = __shfl(w1, sl0 + 6);
            float ws0 = head0 ? w00 : w10;
            float ws1 = head0 ? w01 : w11;
            float ws2 = head0 ? w02 : w12;
            float ws3 = head0 ? w03 : w13;
            uint4 r0 = *(const uint4*)(hbase + (size_t)sj0 * 128);
            uint4 r1 = *(const uint4*)(hbase + (size_t)sj1 * 128);
            uint4 r2 = *(const uint4*)(hbase + (size_t)sj2 * 128);
            uint4 r3 = *(const uint4*)(hbase + (size_t)sj3 * 128);
            const _Float16* h0 = (const _Float16*)&r0;
            const _Float16* h1 = (const _Float16*)&r1;
            const _Float16* h2 = (const _Float16*)&r2;
            const _Float16* h3 = (const _Float16*)&r3;
            #pragma unroll
            for (int k = 0; k < 8; ++k) acc[k] += ws0 * (float)h0[k];
            #pragma unroll
            for (int k = 0; k < 8; ++k) acc[k] += ws1 * (float)h1[k];
            #pragma unroll
            for (int k = 0; k < 8; ++k) acc[k] += ws2 * (float)h2[k];
            #pragma unroll
            for (int k = 0; k < 8; ++k) acc[k] += ws3 * (float)h3[k];
            dsum += (ws0 + ws1) + (ws2 + ws3);
        }
        for (; jj + 2 <= iters; jj += 2) {
            int sl0 = hb + (jj << 1) + q;
            int sj0 = __shfl(s, sl0), sj1 = __shfl(s, sl0 + 2);
            float w00 = __shfl(w0, sl0),     w10 = __shfl(w1, sl0);
            float w01 = __shfl(w0, sl0 + 2), w11 = __shfl(w1, sl0 + 2);
            float ws0 = head0 ? w00 : w10;
            float ws1 = head0 ? w01 : w11;
            uint4 r0 = *(const uint4*)(hbase + (size_t)sj0 * 128);
            uint4 r1 = *(const uint4*)(hbase + (size_t)sj1 * 128);
            const _Float16* h0 = (const _Float16*)&r0;
            const _Float16* h1 = (const _Float16*)&r1;
            #pragma unroll
            for (int k = 0; k < 8; ++k) acc[k] += ws0 * (float)h0[k];
            #pragma unroll
            for (int k = 0; k < 8; ++k) acc[k] += ws1 * (float)h1[k];
            dsum += ws0 + ws1;
        }
        if (jj < iters) {
            int sl = hb + (jj << 1) + q;
            int   sj = __shfl(s,  sl);
            float wa = __shfl(w0, sl);
            float wb = __shfl(w1, sl);
            float ws = head0 ? wa : wb;
            uint4 raw = *(const uint4*)(hbase + (size_t)sj * 128);
            const _Float16* h = (const _Float16*)&raw;
            #pragma unroll
            for (int k = 0; k < 8; ++k) acc[k] += ws * (float)h[k];
            dsum += ws;
        }
    }

    // merge the two q-groups within each half (NOT across halves!)
    #pragma unroll
    for (int k = 0; k < 8; ++k) acc[k] += __shfl_xor(acc[k], 16);
    dsum += __shfl_xor(dsum, 16);

    if (q == 0 && active) {
        float inv = 1.f / dsum;
        int c0 = p * 8;
        float v[8];
        #pragma unroll
        for (int k = 0; k < 8; ++k) v[k] = acc[k] * inv + bias[c0 + k];
        if (mode >= 1) {
            half8 pv = *(const half8*)(prev + (size_t)node * 128 + c0);
            #pragma unroll
            for (int k = 0; k < 8; ++k) v[k] += (float)pv[k];
        }
        #pragma unroll
        for (int k = 0; k < 8; ++k) v[k] = v[k] > 0.f ? v[k] : LEAK * v[k];
        if (mode == 2) {
            float partial = 0.f;
            #pragma unroll
            for (int k = 0; k < 8; ++k) partial += v[k] * lw[c0 + k];
            partial += __shfl_xor(partial, 1);
            partial += __shfl_xor(partial, 2);
            partial += __shfl_xor(partial, 4);
            partial += __shfl_xor(partial, 8);
            if (hl == 0) logits[node] = partial + lb[0];
        } else {
            half8 ov;
            #pragma unroll
            for (int k = 0; k < 8; ++k) ov[k] = (_Float16)v[k];
            *(half8*)(Out + (size_t)node * 128 + c0) = ov;
        }
    }
}

// ================= launch =================

extern "C" void kernel_launch(void* const* d_in, const int* in_sizes, int n_in,
                              void* d_out, int out_size, void* d_ws, size_t ws_size,
                              hipStream_t stream) {
    const float* x    = (const float*)d_in[0];
    const int*   edge = (const int*)d_in[1];
    const float* W[3]  = {(const float*)d_in[2], (const float*)d_in[6], (const float*)d_in[10]};
    const float* as[3] = {(const float*)d_in[3], (const float*)d_in[7], (const float*)d_in[11]};
    const float* ad[3] = {(const float*)d_in[4], (const float*)d_in[8], (const float*)d_in[12]};
    const float* bs[3] = {(const float*)d_in[5], (const float*)d_in[9], (const float*)d_in[13]};
    const float* lw = (const float*)d_in[14];
    const float* lb = (const float*)d_in[15];

    const int N    = in_sizes[0] / 128;
    const int E    = in_sizes[1] / 2;
    const int ETOT = E + N;
    const int NBK  = (N + 127) >> 7;   // requires N <= 65536 (here N = 50000)

    char* base = (char*)d_ws;
    size_t o = 0;
    auto carve = [&](size_t bytes) {
        char* p = base + o;
        o = (o + bytes + 255) & ~(size_t)255;
        return p;
    };
    int*      off    = (int*)     carve((size_t)N * 4);
    int*      endv   = (int*)     carve((size_t)N * 4);
    int*      gcnt   = (int*)     carve((size_t)NBK * 4);
    unsigned* binned = (unsigned*)carve((size_t)NBK * BCAP * 4);
    int*      csr    = (int*)     carve((size_t)NBK * BCAP * 4);
    float*    alsrc  = (float*)   carve((size_t)N * 2 * 4);
    float*    aldst  = (float*)   carve((size_t)N * 2 * 4);
    _Float16* h16    = (_Float16*)carve((size_t)N * 128 * 2);
    _Float16* bufA   = (_Float16*)carve((size_t)N * 128 * 2);
    _Float16* bufB   = (_Float16*)carve((size_t)N * 128 * 2);
    _Float16* w16t   = (_Float16*)carve((size_t)3 * 16384 * 2);
    (void)ws_size; (void)n_in; (void)out_size;

    const int* esrc = edge;
    const int* edst = edge + E;

    int eb = (ETOT + 4095) / 4096;

    hipMemsetAsync(gcnt, 0, (size_t)NBK * 4, stream);

    // fused binning + W transpose, then per-bucket CSR finalize (2 dispatches)
    k_binscatter<<<eb + 12, 256, 0, stream>>>(esrc, edst, gcnt, binned, E, ETOT, NBK, eb,
                                              W[0], W[1], W[2], w16t);
    k_scatter2<<<NBK, 256, 0, stream>>>(binned, gcnt, off, endv, csr, N);

    int gemm_blocks = (N + 63) / 64;
    int agg_blocks  = (N + 7) / 8;     // 2 nodes per wave, 4 waves per block

    // layer 1 (fp32 input)
    k_gemm_mfma<<<gemm_blocks, 256, 0, stream>>>(x, 0, w16t, as[0], ad[0], h16, alsrc, aldst, N);
    k_aggregate<<<agg_blocks, 256, 0, stream>>>(h16, alsrc, aldst, off, endv, csr,
                                                bs[0], nullptr, bufA, lw, lb, nullptr, N, 0);
    // layer 2 (fp16 input)
    k_gemm_mfma<<<gemm_blocks, 256, 0, stream>>>(bufA, 1, w16t + 16384, as[1], ad[1], h16, alsrc, aldst, N);
    k_aggregate<<<agg_blocks, 256, 0, stream>>>(h16, alsrc, aldst, off, endv, csr,
                                                bs[1], bufA, bufB, lw, lb, nullptr, N, 1);
    // layer 3 (fp16 input, + fused final linear)
    k_gemm_mfma<<<gemm_blocks, 256, 0, stream>>>(bufB, 1, w16t + 32768, as[2], ad[2], h16, alsrc, aldst, N);
    k_aggregate<<<agg_blocks, 256, 0, stream>>>(h16, alsrc, aldst, off, endv, csr,
                                                bs[2], bufB, nullptr, lw, lb, (float*)d_out, N, 2);
}